// Round 7
// baseline (1058.208 us; speedup 1.0000x reference)
//
#include <hip/hip_runtime.h>
#include <stdint.h>

#define B_ 16
#define C_ 256
#define HW_ 4096
#define P_ 65536
#define S_ 21
#define Q_ 256
#define N_ 256
#define THR_ 0.97f
#define TINY_ 1.17549435e-38f

// ---------------- threefry-2x32, 20 rounds (matches JAX/Random123) ----------
__device__ __forceinline__ void tf2x32(uint32_t k0, uint32_t k1,
                                       uint32_t& x0, uint32_t& x1) {
  uint32_t k2 = k0 ^ k1 ^ 0x1BD11BDAu;
  uint32_t v0 = x0 + k0, v1 = x1 + k1;
#define TFR(r) { v0 += v1; v1 = (v1 << (r)) | (v1 >> (32 - (r))); v1 ^= v0; }
  TFR(13) TFR(15) TFR(26) TFR(6)  v0 += k1; v1 += k2 + 1u;
  TFR(17) TFR(29) TFR(16) TFR(24) v0 += k2; v1 += k0 + 2u;
  TFR(13) TFR(15) TFR(26) TFR(6)  v0 += k0; v1 += k1 + 3u;
  TFR(17) TFR(29) TFR(16) TFR(24) v0 += k1; v1 += k2 + 4u;
  TFR(13) TFR(15) TFR(26) TFR(6)  v0 += k2; v1 += k0 + 5u;
#undef TFR
  x0 = v0; x1 = v1;
}

__device__ __forceinline__ uint32_t tf_xor(uint32_t k0, uint32_t k1,
                                           uint32_t hi, uint32_t lo) {
  uint32_t a = hi, b = lo;
  tf2x32(k0, k1, a, b);
  return a ^ b;
}

// JAX uniform [0,1): ((bits>>9)|0x3f800000).view(f32) - 1
__device__ __forceinline__ float u01(uint32_t bits) {
  return __uint_as_float((bits >> 9) | 0x3f800000u) - 1.0f;
}

#define C1M_ (12.0f / 255.0f)   // mu dequant: m = qm*C1M - 6
#define C2S_ (0.9f / 255.0f)    // sigma dequant: s = 0.1 + qs*C2S

// ---------------- fast: segid/hardf only (no mu read) -----------------------
__global__ __launch_bounds__(256) void k_prep_light(
    const float* __restrict__ label, const float* __restrict__ maskp,
    const float* __restrict__ prob,
    int* __restrict__ segid, int* __restrict__ hardf) {
  int p = blockIdx.x * 256 + threadIdx.x;
  int b = p >> 12, hw = p & 4095;
  float mv = maskp[p];
  int seg = -1, hf = 0;
  if (mv > 0.0f) {
    for (int s = 0; s < S_; ++s) {
      float lv = label[(size_t)((b * S_ + s) << 12) + hw];
      if (lv > 0.0f) {
        seg = s;
        hf = (prob[(size_t)((b * S_ + s) << 12) + hw] < THR_) ? 1 : 0;
      }
    }
  }
  segid[p] = seg; hardf[p] = hf;
}

// ---------------- slow-path prep (also computes denom) ----------------------
__global__ __launch_bounds__(256) void k_prep(
    const float* __restrict__ mu, const float* __restrict__ label,
    const float* __restrict__ maskp, const float* __restrict__ prob,
    float* __restrict__ denom, int* __restrict__ segid, int* __restrict__ hardf) {
  int p = blockIdx.x * 256 + threadIdx.x;
  int b = p >> 12, hw = p & 4095;
  float mv = maskp[p];
  int seg = -1, hf = 0;
  if (mv > 0.0f) {
    for (int s = 0; s < S_; ++s) {
      float lv = label[(size_t)((b * S_ + s) << 12) + hw];
      if (lv > 0.0f) {
        seg = s;
        hf = (prob[(size_t)((b * S_ + s) << 12) + hw] < THR_) ? 1 : 0;
      }
    }
  }
  segid[p] = seg; hardf[p] = hf;
  float ss = 0.0f;
  const float* mb = mu + ((size_t)b << 20) + hw;
  for (int c = 0; c < C_; ++c) {
    float v = mb[(size_t)c << 12];
    ss += v * v;
  }
  denom[p] = fmaxf(sqrtf(ss), 1e-12f);
}

// ---------------- counting sort phase 1 -------------------------------------
__global__ __launch_bounds__(256) void k_count(
    const int* __restrict__ segid, const int* __restrict__ hardf,
    int* __restrict__ countsV, int* __restrict__ countsH) {
  __shared__ int cV[S_], cH[S_];
  int tid = threadIdx.x;
  if (tid < S_) { cV[tid] = 0; cH[tid] = 0; }
  __syncthreads();
  int p = blockIdx.x * 256 + tid;
  int s = segid[p];
  if (s >= 0) {
    atomicAdd(&cV[s], 1);
    if (hardf[p]) atomicAdd(&cH[s], 1);
  }
  __syncthreads();
  if (tid < S_) {
    countsV[blockIdx.x * S_ + tid] = cV[tid];
    countsH[blockIdx.x * S_ + tid] = cH[tid];
  }
}

// ---------------- counting sort phase 2 -------------------------------------
__global__ __launch_bounds__(64) void k_scan(
    const int* __restrict__ countsV, const int* __restrict__ countsH,
    int* __restrict__ offsV, int* __restrict__ offsH,
    int* __restrict__ vcount, int* __restrict__ hcount) {
  int t = threadIdx.x;
  if (t >= 2 * S_) return;
  int s = (t < S_) ? t : (t - S_);
  bool isH = (t >= S_);
  const int* cnt = isH ? countsH : countsV;
  int* offs = isH ? offsH : offsV;
  int acc = 0;
  for (int bo = 0; bo < 256; ++bo) {
    offs[bo * S_ + s] = acc;
    acc += cnt[bo * S_ + s];
  }
  if (isH) hcount[s] = acc; else vcount[s] = acc;
}

// ---------------- counting sort phase 3: stable scatter ---------------------
__global__ __launch_bounds__(256) void k_scatter(
    const int* __restrict__ segid, const int* __restrict__ hardf,
    const int* __restrict__ offsV, const int* __restrict__ offsH,
    int* __restrict__ vlist, int* __restrict__ hlist) {
  __shared__ int wcV[4][S_], wcH[4][S_];
  __shared__ int wbV[4][S_], wbH[4][S_];
  int tid = threadIdx.x, lane = tid & 63, w = tid >> 6;
  int p = blockIdx.x * 256 + tid;
  int seg = segid[p];
  bool hard = (seg >= 0) && (hardf[p] != 0);
  unsigned long long lt = ((unsigned long long)1 << lane) - 1ull;
  int rankV = 0, rankH = 0;
  for (int s = 0; s < S_; ++s) {
    unsigned long long mV = __ballot(seg == s);
    unsigned long long mH = __ballot(hard && (seg == s));
    if (lane == 0) { wcV[w][s] = __popcll(mV); wcH[w][s] = __popcll(mH); }
    if (seg == s) { rankV = __popcll(mV & lt); rankH = __popcll(mH & lt); }
  }
  __syncthreads();
  if (tid < S_) {
    int aV = 0, aH = 0;
    for (int ww = 0; ww < 4; ++ww) {
      int t1 = wcV[ww][tid]; wbV[ww][tid] = aV; aV += t1;
      int t2 = wcH[ww][tid]; wbH[ww][tid] = aH; aH += t2;
    }
  }
  __syncthreads();
  if (seg >= 0) {
    vlist[seg * P_ + offsV[blockIdx.x * S_ + seg] + wbV[w][seg] + rankV] = p;
    if (hard)
      hlist[seg * P_ + offsH[blockIdx.x * S_ + seg] + wbH[w][seg] + rankH] = p;
  }
}

// ------- transpose -> u8 feat + LDS-atomic proto partials + sumsq -----------
// feat[p][cpair] u32 = [qm(2c), qs(2c), qm(2c+1), qs(2c+1)], row = 512 B.
// partS[slice (=bx&31)][c*42 + s*2 + t] accumulated with global atomics.
__global__ __launch_bounds__(256) void k_transpose(
    const float* __restrict__ mu, const float* __restrict__ sigma,
    const int* __restrict__ segid,
    uint32_t* __restrict__ feat, float* __restrict__ partS,
    float* __restrict__ ssqp) {
  __shared__ float tmu[64][65];
  __shared__ float tsg[64][65];
  __shared__ int sseg[64];
  __shared__ float accA[S_][64];
  __shared__ float accB[S_][64];
  __shared__ float ssq[4][64];
  int tid = threadIdx.x;
  int p0 = blockIdx.x * 64;
  int c0 = blockIdx.y * 64;
  int b = p0 >> 12, hw0 = p0 & 4095;
  if (tid < 64) sseg[tid] = segid[p0 + tid];
  for (int k = tid; k < S_ * 64; k += 256) {
    ((float*)accA)[k] = 0.0f;
    ((float*)accB)[k] = 0.0f;
  }
  // vectorized loads: thread = (cl = tid>>4, x4 = tid&15), float4 along hw
  {
    int cl = tid >> 4, x4 = tid & 15;
    const size_t basein = ((size_t)b << 20) + (size_t)(hw0 + x4 * 4);
    for (int it = 0; it < 4; ++it) {
      int cc = it * 16 + cl;
      size_t a = basein + ((size_t)(c0 + cc) << 12);
      float4 vm = *(const float4*)(mu + a);
      float4 vs = *(const float4*)(sigma + a);
      int px = x4 * 4;
      tmu[cc][px] = vm.x; tmu[cc][px + 1] = vm.y;
      tmu[cc][px + 2] = vm.z; tmu[cc][px + 3] = vm.w;
      tsg[cc][px] = vs.x; tsg[cc][px + 1] = vs.y;
      tsg[cc][px + 2] = vs.z; tsg[cc][px + 3] = vs.w;
    }
  }
  __syncthreads();
  // per-pixel partial sum of squares (quarter of channels per thread)
  {
    int qq = tid >> 6, px = tid & 63;
    float s = 0.0f;
    for (int cc = qq * 16; cc < qq * 16 + 16; ++cc) {
      float v = tmu[cc][px];
      s = fmaf(v, v, s);
    }
    ssq[qq][px] = s;
  }
  // proto partials: thread (qq = tid>>6, cc = tid&63), LDS atomics
  {
    int qq = tid >> 6, cc = tid & 63;
    for (int pp = qq * 16; pp < qq * 16 + 16; ++pp) {
      int s = sseg[pp];
      if (s >= 0) {
        float inv = 1.0f / tsg[cc][pp];
        atomicAdd(&accA[s][cc], inv);
        atomicAdd(&accB[s][cc], tmu[cc][pp] * inv);
      }
    }
  }
  // u8 feat pack: 8 iters, thread = (p = tid>>5 + 8*it, u = tid&31)
  for (int it = 0; it < 8; ++it) {
    int p = (tid >> 5) + it * 8;
    int u = tid & 31;
    float m0 = tmu[2 * u][p], s0 = tsg[2 * u][p];
    float m1 = tmu[2 * u + 1][p], s1 = tsg[2 * u + 1][p];
    uint32_t qm0 = (uint32_t)min(max(__float2int_rn((m0 + 6.0f) * (255.0f / 12.0f)), 0), 255);
    uint32_t qs0 = (uint32_t)min(max(__float2int_rn((s0 - 0.1f) * (255.0f / 0.9f)), 0), 255);
    uint32_t qm1 = (uint32_t)min(max(__float2int_rn((m1 + 6.0f) * (255.0f / 12.0f)), 0), 255);
    uint32_t qs1 = (uint32_t)min(max(__float2int_rn((s1 - 0.1f) * (255.0f / 0.9f)), 0), 255);
    feat[(size_t)(p0 + p) * 128 + (c0 >> 1) + u] =
        qm0 | (qs0 << 8) | (qm1 << 16) | (qs1 << 24);
  }
  __syncthreads();
  if (tid < 64)
    ssqp[(size_t)blockIdx.y * P_ + p0 + tid] =
        ssq[0][tid] + ssq[1][tid] + ssq[2][tid] + ssq[3][tid];
  // flush proto partials to a 32-slice global buffer
  {
    float* dst = partS + (size_t)(blockIdx.x & 31) * 10752;
    for (int k = tid; k < S_ * 64; k += 256) {
      int s = k >> 6, cc = k & 63;
      int c = c0 + cc;
      atomicAdd(&dst[c * 42 + s * 2], accA[s][cc]);
      atomicAdd(&dst[c * 42 + s * 2 + 1], accB[s][cc]);
    }
  }
}

// ---------------- finalize per-pixel reciprocal norms -----------------------
__global__ __launch_bounds__(256) void k_norm_fin(
    const float* __restrict__ ssqp, float* __restrict__ rdn) {
  int p = blockIdx.x * 256 + threadIdx.x;
  float s = ssqp[p] + ssqp[P_ + p] + ssqp[2 * P_ + p] + ssqp[3 * P_ + p];
  rdn[p] = 1.0f / fmaxf(sqrtf(s), 1e-12f);
}

// ---------------- reduce 32 proto slices ------------------------------------
__global__ __launch_bounds__(256) void k_reduceS(
    const float* __restrict__ partS, float* __restrict__ proto_acc) {
  int j = blockIdx.x * 256 + threadIdx.x;    // 42 blocks x 256 = 10752
  float s = 0.0f;
  for (int sl = 0; sl < 32; ++sl) s += partS[(size_t)sl * 10752 + j];
  proto_acc[j] = s;
}

// ------- fallback proto accumulation (small-workspace path) -----------------
__global__ __launch_bounds__(256) void k_proto_acc(
    const float* __restrict__ mu, const float* __restrict__ sigma,
    const int* __restrict__ segid, float* __restrict__ proto_acc) {
  __shared__ float acc[256][42];
  int c = blockIdx.x, tid = threadIdx.x;
  for (int k = 0; k < 42; ++k) acc[tid][k] = 0.0f;
  for (int it = 0; it < 256; ++it) {
    int p = it * 256 + tid;
    int s = segid[p];
    if (s >= 0) {
      int b = p >> 12, hw = p & 4095;
      size_t o = ((size_t)b << 20) + ((size_t)c << 12) + (size_t)hw;
      float inv = 1.0f / sigma[o];
      acc[tid][s * 2] += inv;
      acc[tid][s * 2 + 1] += mu[o] * inv;
    }
  }
  __syncthreads();
  if (tid < 42) {
    float t = 0.0f;
    for (int r = 0; r < 256; ++r) t += acc[r][tid];
    proto_acc[c * 42 + tid] = t;
  }
}

// ---------------- finalize protos (normalized mu, sigma) --------------------
__global__ __launch_bounds__(256) void k_proto_fin(
    const float* __restrict__ proto_acc,
    float* __restrict__ pmn, float* __restrict__ psig) {
  __shared__ float red[256];
  __shared__ float dsh;
  int s = blockIdx.x, c = threadIdx.x;
  float sx = proto_acc[c * 42 + s * 2];
  float sy = proto_acc[c * 42 + s * 2 + 1];
  float ps = 1.0f / sx;
  float pm = ps * sy;
  red[c] = pm * pm;
  __syncthreads();
  for (int st = 128; st > 0; st >>= 1) {
    if (c < st) red[c] += red[c + st];
    __syncthreads();
  }
  if (c == 0) dsh = fmaxf(sqrtf(red[0]), 1e-12f);
  __syncthreads();
  pmn[s * 256 + c] = pm / dsh;
  psig[s * 256 + c] = ps;
}

// ---------------- proto similarity -> log_softmax ---------------------------
__global__ __launch_bounds__(256) void k_logp(
    const float* __restrict__ pmn, const float* __restrict__ psig,
    float* __restrict__ logp) {
  __shared__ float red[256];
  __shared__ float sim[20];
  int i = blockIdx.x, c = threadIdx.x;
  float pmi = pmn[i * 256 + c];
  float psi = psig[i * 256 + c];
  for (int t = 0; t < 20; ++t) {
    int o = (i + 1 + t) % S_;
    float d = pmi - pmn[o * 256 + c];
    float sdn = psi + psig[o * 256 + c];
    red[c] = d * d / sdn + __logf(sdn);
    __syncthreads();
    for (int st = 128; st > 0; st >>= 1) {
      if (c < st) red[c] += red[c + st];
      __syncthreads();
    }
    if (c == 0) sim[t] = -red[0] * (1.0f / 256.0f);
    __syncthreads();
  }
  if (c == 0) {
    float mx = -3.4e38f;
    for (int t = 0; t < 20; ++t) mx = fmaxf(mx, sim[t]);
    float se = 0.0f;
    for (int t = 0; t < 20; ++t) se += __expf(sim[t] - mx);
    float ls = __logf(se);
    for (int t = 0; t < 20; ++t) logp[i * 20 + t] = sim[t] - mx - ls;
  }
}

// ---------------- main: fast path (u8 feat, 16 lanes/logit) -----------------
__global__ __launch_bounds__(256) void k_main_fast(
    const uint32_t* __restrict__ feat, const float* __restrict__ rdn,
    const float* __restrict__ pmn, const float* __restrict__ psig,
    const float* __restrict__ logp,
    const int* __restrict__ vlist, const int* __restrict__ hlist,
    const int* __restrict__ vcount, const int* __restrict__ hcount,
    float* __restrict__ partials) {
  int q = blockIdx.x, i = blockIdx.y;
  int tid = threadIdx.x, lane = tid & 63, wid = tid >> 6;
  int hc = hcount[i];
  if (hc <= 0) { if (tid == 0) partials[i * Q_ + q] = 0.0f; return; }

  __shared__ float amu[256];     // normalized anchor mu
  __shared__ float asgp[256];    // anchor sigma + 0.1
  __shared__ int nidx[256];
  __shared__ float lgp[20];
  __shared__ float lgt[257];
  __shared__ float wsum[4];

  // key = fold_in(key(42), i); k1,k2,k3 = split (partitionable)
  uint32_t kf0 = 0u, kf1 = (uint32_t)i;
  tf2x32(0u, 42u, kf0, kf1);
  uint32_t k1a = 0u, k1b = 0u; tf2x32(kf0, kf1, k1a, k1b);
  uint32_t k2a = 0u, k2b = 1u; tf2x32(kf0, kf1, k2a, k2b);
  uint32_t k3a = 0u, k3b = 2u; tf2x32(kf0, kf1, k3a, k3b);

  // anchor
  uint32_t ab = tf_xor(k1a, k1b, 0u, (uint32_t)q);
  float ua = fmaxf(0.0f, u01(ab));
  int jq = (int)(ua * (float)hc);
  jq = min(max(jq, 0), hc - 1);
  int a_idx = hlist[i * P_ + jq];
  float rdn_a = rdn[a_idx];
  if (tid < 128) {
    uint32_t v = feat[(size_t)a_idx * 128 + tid];
    float qm0 = (float)(v & 255u), qs0 = (float)((v >> 8) & 255u);
    float qm1 = (float)((v >> 16) & 255u), qs1 = (float)((v >> 24) & 255u);
    amu[2 * tid] = fmaf(qm0, C1M_, -6.0f) * rdn_a;
    amu[2 * tid + 1] = fmaf(qm1, C1M_, -6.0f) * rdn_a;
    asgp[2 * tid] = fmaf(qs0, C2S_, 0.2f);
    asgp[2 * tid + 1] = fmaf(qs1, C2S_, 0.2f);
  }
  if (tid < 20) lgp[tid] = logp[i * 20 + tid];
  __syncthreads();

  // negative sampling: thread tid == n. Gumbel-argmax over 20 classes.
  {
    int n = tid;
    uint32_t base = ((uint32_t)q * 256u + (uint32_t)n) * 20u;
    float best = -3.4e38f; int arg = 0;
    for (int t = 0; t < 20; ++t) {
      uint32_t bits = tf_xor(k2a, k2b, 0u, base + (uint32_t)t);
      float f = u01(bits);
      float u = fmaxf(TINY_, f + TINY_);
      float g = -__logf(-__logf(u));
      float sc = g + lgp[t];
      if (sc > best) { best = sc; arg = t; }
    }
    int nseg = (i + 1 + arg) % S_;
    int cnt = vcount[nseg];
    uint32_t b3 = tf_xor(k3a, k3b, 0u, (uint32_t)q * 256u + (uint32_t)n);
    float u3 = fmaxf(0.0f, u01(b3));
    int jp = (int)(u3 * (float)cnt);
    jp = min(max(jp, 0), max(cnt - 1, 0));
    nidx[n] = vlist[nseg * P_ + jp];
  }
  // proto logit (j = 0) from f32 protos
  {
    float d = amu[tid] - pmn[i * 256 + tid];
    float s = asgp[tid] - 0.1f + psig[i * 256 + tid];
    float term = d * d / s + __logf(s);
    for (int off = 32; off > 0; off >>= 1) term += __shfl_xor(term, off, 64);
    if (lane == 0) wsum[wid] = term;
  }
  __syncthreads();
  if (tid == 0) lgt[0] = -(wsum[0] + wsum[1] + wsum[2] + wsum[3]) * (1.0f / 256.0f);

  // 16 lanes per logit; lane t owns channels 8t..8t+7 and 128+8t..128+8t+7
  int t = lane & 15;
  int g = (wid << 2) | (lane >> 4);
  float amr[16], asr[16];
#pragma unroll
  for (int k = 0; k < 8; ++k) {
    amr[k] = amu[8 * t + k];
    asr[k] = asgp[8 * t + k];
    amr[8 + k] = amu[128 + 8 * t + k];
    asr[8 + k] = asgp[128 + 8 * t + k];
  }
  for (int iter = 0; iter < 16; ++iter) {
    int j = iter * 16 + g;
    int rid = nidx[j];
    float rb = rdn[rid];
    float arb = 6.0f * rb;
    float crb = C1M_ * rb;
    const uint32_t* __restrict__ row = feat + (size_t)rid * 128;
    uint4 v0 = *(const uint4*)(row + 4 * t);
    uint4 v1 = *(const uint4*)(row + 64 + 4 * t);
    float acc = 0.0f, pacc = 1.0f;
#define CH2(vv, kb)                                                          \
    {                                                                        \
      float qm0 = (float)((vv) & 255u), qs0 = (float)(((vv) >> 8) & 255u);   \
      float qm1 = (float)(((vv) >> 16) & 255u), qs1 = (float)((vv) >> 24);   \
      float d0 = fmaf(qm0, -crb, amr[kb] + arb);                             \
      float s0 = fmaf(qs0, C2S_, asr[kb]);                                   \
      float d1 = fmaf(qm1, -crb, amr[kb + 1] + arb);                         \
      float s1 = fmaf(qs1, C2S_, asr[kb + 1]);                               \
      acc = fmaf(d0 * d0, __builtin_amdgcn_rcpf(s0), acc);                   \
      acc = fmaf(d1 * d1, __builtin_amdgcn_rcpf(s1), acc);                   \
      pacc *= s0 * s1;                                                       \
    }
    CH2(v0.x, 0) CH2(v0.y, 2) CH2(v0.z, 4) CH2(v0.w, 6)
    CH2(v1.x, 8) CH2(v1.y, 10) CH2(v1.z, 12) CH2(v1.w, 14)
#undef CH2
    acc += __logf(pacc);   // 16 s-values in [0.2,2.2]: product in f32 range
    acc += __shfl_xor(acc, 1, 64);
    acc += __shfl_xor(acc, 2, 64);
    acc += __shfl_xor(acc, 4, 64);
    acc += __shfl_xor(acc, 8, 64);
    if (t == 0) lgt[1 + j] = -acc * (1.0f / 256.0f);
  }
  __syncthreads();

  if (wid == 0) {
    float mx = -3.4e38f;
    for (int j2 = lane; j2 < 257; j2 += 64) mx = fmaxf(mx, lgt[j2]);
    for (int off = 32; off > 0; off >>= 1) mx = fmaxf(mx, __shfl_xor(mx, off, 64));
    float se = 0.0f;
    for (int j2 = lane; j2 < 257; j2 += 64) se += __expf(lgt[j2] - mx);
    for (int off = 32; off > 0; off >>= 1) se += __shfl_xor(se, off, 64);
    if (lane == 0) partials[i * Q_ + q] = __logf(se) + mx - lgt[0];
  }
}

// ---------------- main: slow fallback (NCHW gather) -------------------------
__global__ __launch_bounds__(256) void k_main_slow(
    const float* __restrict__ mu, const float* __restrict__ sigma,
    const float* __restrict__ denom,
    const float* __restrict__ pmn, const float* __restrict__ psig,
    const float* __restrict__ logp,
    const int* __restrict__ vlist, const int* __restrict__ hlist,
    const int* __restrict__ vcount, const int* __restrict__ hcount,
    float* __restrict__ partials) {
  int q = blockIdx.x, i = blockIdx.y;
  int tid = threadIdx.x, lane = tid & 63, wid = tid >> 6;
  int hc = hcount[i];
  if (hc <= 0) { if (tid == 0) partials[i * Q_ + q] = 0.0f; return; }

  __shared__ __align__(16) float amu[256];
  __shared__ __align__(16) float asg[256];
  __shared__ int nidx[256];
  __shared__ float lgp[20];
  __shared__ float lgt[257];

  uint32_t kf0 = 0u, kf1 = (uint32_t)i;
  tf2x32(0u, 42u, kf0, kf1);
  uint32_t k1a = 0u, k1b = 0u; tf2x32(kf0, kf1, k1a, k1b);
  uint32_t k2a = 0u, k2b = 1u; tf2x32(kf0, kf1, k2a, k2b);
  uint32_t k3a = 0u, k3b = 2u; tf2x32(kf0, kf1, k3a, k3b);

  uint32_t ab = tf_xor(k1a, k1b, 0u, (uint32_t)q);
  float ua = fmaxf(0.0f, u01(ab));
  int jq = (int)(ua * (float)hc);
  jq = min(max(jq, 0), hc - 1);
  int a_idx = hlist[i * P_ + jq];
  {
    int b = a_idx >> 12, hw = a_idx & 4095;
    float rdnv = 1.0f / denom[a_idx];
    size_t base = ((size_t)b << 20) + (size_t)hw + ((size_t)tid << 12);
    amu[tid] = mu[base] * rdnv;
    asg[tid] = sigma[base];
  }
  if (tid < 20) lgp[tid] = logp[i * 20 + tid];
  __syncthreads();

  {
    int n = tid;
    uint32_t base = ((uint32_t)q * 256u + (uint32_t)n) * 20u;
    float best = -3.4e38f; int arg = 0;
    for (int t = 0; t < 20; ++t) {
      uint32_t bits = tf_xor(k2a, k2b, 0u, base + (uint32_t)t);
      float f = u01(bits);
      float u = fmaxf(TINY_, f + TINY_);
      float g = -__logf(-__logf(u));
      float sc = g + lgp[t];
      if (sc > best) { best = sc; arg = t; }
    }
    int nseg = (i + 1 + arg) % S_;
    int cnt = vcount[nseg];
    uint32_t b3 = tf_xor(k3a, k3b, 0u, (uint32_t)q * 256u + (uint32_t)n);
    float u3 = fmaxf(0.0f, u01(b3));
    int jp = (int)(u3 * (float)cnt);
    jp = min(max(jp, 0), max(cnt - 1, 0));
    nidx[n] = vlist[nseg * P_ + jp];
  }
  __syncthreads();

  int c0 = lane * 4;
  float4 am4 = *(const float4*)(amu + c0);
  float4 as4 = *(const float4*)(asg + c0);
  for (int j = wid; j < 257; j += 4) {
    float bm0, bm1, bm2, bm3, bs0, bs1, bs2, bs3;
    if (j == 0) {
      float4 bm4 = *(const float4*)(pmn + i * 256 + c0);
      float4 bs4 = *(const float4*)(psig + i * 256 + c0);
      bm0 = bm4.x; bm1 = bm4.y; bm2 = bm4.z; bm3 = bm4.w;
      bs0 = bs4.x; bs1 = bs4.y; bs2 = bs4.z; bs3 = bs4.w;
    } else {
      int pix = nidx[j - 1];
      int b = pix >> 12, hw = pix & 4095;
      float rdnv = 1.0f / denom[pix];
      size_t base = ((size_t)b << 20) + (size_t)hw + ((size_t)(c0) << 12);
      bm0 = mu[base] * rdnv;          bs0 = sigma[base];
      bm1 = mu[base + 4096] * rdnv;   bs1 = sigma[base + 4096];
      bm2 = mu[base + 8192] * rdnv;   bs2 = sigma[base + 8192];
      bm3 = mu[base + 12288] * rdnv;  bs3 = sigma[base + 12288];
    }
    float d0 = am4.x - bm0, s0 = as4.x + bs0;
    float d1 = am4.y - bm1, s1 = as4.y + bs1;
    float d2 = am4.z - bm2, s2 = as4.z + bs2;
    float d3 = am4.w - bm3, s3 = as4.w + bs3;
    float acc = d0 * d0 / s0 + __logf(s0);
    acc += d1 * d1 / s1 + __logf(s1);
    acc += d2 * d2 / s2 + __logf(s2);
    acc += d3 * d3 / s3 + __logf(s3);
    for (int off = 32; off > 0; off >>= 1) acc += __shfl_xor(acc, off, 64);
    if (lane == 0) lgt[j] = -acc * (1.0f / 256.0f);
  }
  __syncthreads();

  if (wid == 0) {
    float mx = -3.4e38f;
    for (int j = lane; j < 257; j += 64) mx = fmaxf(mx, lgt[j]);
    for (int off = 32; off > 0; off >>= 1) mx = fmaxf(mx, __shfl_xor(mx, off, 64));
    float se = 0.0f;
    for (int j = lane; j < 257; j += 64) se += __expf(lgt[j] - mx);
    for (int off = 32; off > 0; off >>= 1) se += __shfl_xor(se, off, 64);
    if (lane == 0) partials[i * Q_ + q] = __logf(se) + mx - lgt[0];
  }
}

// ---------------- final reduction, dtype-hedged output ----------------------
__global__ __launch_bounds__(256) void k_final(
    const float* __restrict__ partials, const int* __restrict__ vcount,
    const int* __restrict__ hcount, uint32_t* __restrict__ out) {
  __shared__ float ces[S_];
  int tid = threadIdx.x;
  if (tid < S_) {
    float s = 0.0f;
    for (int qq = 0; qq < Q_; ++qq) s += partials[tid * Q_ + qq];
    ces[tid] = (hcount[tid] > 0) ? (s * (1.0f / Q_)) : 0.0f;
  }
  __syncthreads();
  if (tid == 0) {
    float tot = 0.0f, vn = 0.0f;
    for (int s2 = 0; s2 < S_; ++s2) {
      tot += ces[s2];
      if (vcount[s2] > 0) vn += 1.0f;
    }
    float val = tot / vn;
    uint32_t u = __float_as_uint(val);
    uint32_t bf = (u + 0x7FFFu + ((u >> 16) & 1u)) >> 16;
    out[0] = (bf << 16) | bf;
  }
}

extern "C" void kernel_launch(void* const* d_in, const int* in_sizes, int n_in,
                              void* d_out, int out_size, void* d_ws, size_t ws_size,
                              hipStream_t stream) {
  const float* mu    = (const float*)d_in[0];
  const float* sigma = (const float*)d_in[1];
  const float* label = (const float*)d_in[2];
  const float* maskp = (const float*)d_in[3];
  const float* prob  = (const float*)d_in[4];

  char* w = (char*)d_ws;
  size_t off = 0;
  auto alloc = [&](size_t bytes) -> void* {
    off = (off + 255) & ~(size_t)255;
    void* r = w + off;
    off += bytes;
    return r;
  };
  // small buffers (~16 MiB)
  float* denom     = (float*)alloc((size_t)P_ * 4);
  float* rdn       = (float*)alloc((size_t)P_ * 4);
  int*   segid     = (int*)alloc((size_t)P_ * 4);
  int*   hardf     = (int*)alloc((size_t)P_ * 4);
  int*   vlist     = (int*)alloc((size_t)S_ * P_ * 4);
  int*   hlist     = (int*)alloc((size_t)S_ * P_ * 4);
  int*   vcount    = (int*)alloc(S_ * 4);
  int*   hcount    = (int*)alloc(S_ * 4);
  float* proto_acc = (float*)alloc((size_t)C_ * 42 * 4);
  float* pmn       = (float*)alloc((size_t)S_ * C_ * 4);
  float* psig      = (float*)alloc((size_t)S_ * C_ * 4);
  float* logp      = (float*)alloc((size_t)S_ * 20 * 4);
  float* partials  = (float*)alloc((size_t)S_ * Q_ * 4);
  int*   countsV   = (int*)alloc((size_t)256 * S_ * 4);
  int*   countsH   = (int*)alloc((size_t)256 * S_ * 4);
  int*   offsV     = (int*)alloc((size_t)256 * S_ * 4);
  int*   offsH     = (int*)alloc((size_t)256 * S_ * 4);
  float* ssqp      = (float*)alloc((size_t)4 * P_ * 4);
  float* partS     = (float*)alloc((size_t)32 * 10752 * 4);

  // fast-path big buffer: u8 feat, 512 B/row (32 MiB)
  size_t feat_bytes = (size_t)P_ * 128 * 4;
  size_t need = ((off + 255) & ~(size_t)255) + feat_bytes;
  bool fast = (ws_size >= need);
  uint32_t* feat = fast ? (uint32_t*)alloc(feat_bytes) : nullptr;

  if (fast) {
    hipMemsetAsync(partS, 0, (size_t)32 * 10752 * 4, stream);
    k_prep_light<<<P_ / 256, 256, 0, stream>>>(label, maskp, prob, segid, hardf);
    k_count<<<256, 256, 0, stream>>>(segid, hardf, countsV, countsH);
    k_scan<<<1, 64, 0, stream>>>(countsV, countsH, offsV, offsH, vcount, hcount);
    k_scatter<<<256, 256, 0, stream>>>(segid, hardf, offsV, offsH, vlist, hlist);
    k_transpose<<<dim3(P_ / 64, C_ / 64), 256, 0, stream>>>(mu, sigma, segid,
                                                            feat, partS, ssqp);
    k_norm_fin<<<P_ / 256, 256, 0, stream>>>(ssqp, rdn);
    k_reduceS<<<42, 256, 0, stream>>>(partS, proto_acc);
    k_proto_fin<<<S_, 256, 0, stream>>>(proto_acc, pmn, psig);
    k_logp<<<S_, 256, 0, stream>>>(pmn, psig, logp);
    k_main_fast<<<dim3(Q_, S_), 256, 0, stream>>>(feat, rdn, pmn, psig, logp,
                                                  vlist, hlist, vcount, hcount,
                                                  partials);
  } else {
    k_prep<<<P_ / 256, 256, 0, stream>>>(mu, label, maskp, prob, denom, segid, hardf);
    k_count<<<256, 256, 0, stream>>>(segid, hardf, countsV, countsH);
    k_scan<<<1, 64, 0, stream>>>(countsV, countsH, offsV, offsH, vcount, hcount);
    k_scatter<<<256, 256, 0, stream>>>(segid, hardf, offsV, offsH, vlist, hlist);
    k_proto_acc<<<C_, 256, 0, stream>>>(mu, sigma, segid, proto_acc);
    k_proto_fin<<<S_, 256, 0, stream>>>(proto_acc, pmn, psig);
    k_logp<<<S_, 256, 0, stream>>>(pmn, psig, logp);
    k_main_slow<<<dim3(Q_, S_), 256, 0, stream>>>(mu, sigma, denom, pmn, psig, logp,
                                                  vlist, hlist, vcount, hcount,
                                                  partials);
  }
  k_final<<<1, 256, 0, stream>>>(partials, vcount, hcount, (uint32_t*)d_out);
}